// Round 4
// baseline (925.773 us; speedup 1.0000x reference)
//
#include <hip/hip_runtime.h>
#include <hip/hip_bf16.h>
#include <stdint.h>

// ---------------------------------------------------------------------------
// HyperedgeEmbeddingExtractor: gather -> segment mean -> Linear -> LN -> GELU
// FUSED design (round 4): the segment-mean intermediate never leaves the CU.
//   k_zero   : zero begin/end arrays
//   k_bounds : segment boundaries from sorted seg_ids (scatter)
//   k_wsplit : split W fp32 -> bf16 hi/lo, pre-packed in MFMA B-fragment order
//   k_fused  : per block of 64 edges:
//              P1: wave-per-16-edges gather + mean from z, bf16-rounded,
//                  written to LDS A-tile (XOR-swizzled 16B chunks)
//              P2: 2-pass bf16x2 MFMA GEMM (A*Whi + A*Wlo), B double-buffered
//                  via global_load_lds; A LDS-resident (zero restage traffic)
//              P3: fused bias + LayerNorm + exact-erf GELU epilogue
// Numerics: A bf16 (lo-term dropped); W bf16 hi+lo. Est. added err ~3e-3.
// LDS: 64KB A + 2x32KB B + 1.5KB LN = 129.5KB -> 1 block/CU.
// Workspace: ~2.9 MB (bounds + packed W splits).
// ---------------------------------------------------------------------------

typedef __attribute__((ext_vector_type(8))) short short8;
typedef __attribute__((ext_vector_type(8))) unsigned short ushort8;
typedef __attribute__((ext_vector_type(4))) float f32x4;

__device__ __forceinline__ unsigned short f2bf(float f) {
  __hip_bfloat16 h = __float2bfloat16(f);
  return __builtin_bit_cast(unsigned short, h);
}
__device__ __forceinline__ float bf2f(unsigned short u) {
  __hip_bfloat16 h = __builtin_bit_cast(__hip_bfloat16, u);
  return __bfloat162float(h);
}

// async global->LDS, 16B per lane. dst is wave-uniform base (HW adds lane*16).
__device__ __forceinline__ void gld_lds16(const void* g, void* l) {
  __builtin_amdgcn_global_load_lds(
      (const __attribute__((address_space(1))) uint32_t*)g,
      (__attribute__((address_space(3))) uint32_t*)l, 16, 0, 0);
}

// ---------------------------------------------------------------------------
__global__ void k_zero(int* __restrict__ beg, int* __restrict__ end_, int E) {
  int i = blockIdx.x * 256 + threadIdx.x;
  if (i < E) { beg[i] = 0; end_[i] = 0; }
}

__global__ void k_bounds(const int* __restrict__ seg, int* __restrict__ beg,
                         int* __restrict__ end_, int M) {
  int i = blockIdx.x * 256 + threadIdx.x;
  if (i >= M) return;
  int s = seg[i];
  if (i == 0 || seg[i - 1] != s) beg[s] = i;
  if (i == M - 1 || seg[i + 1] != s) end_[s] = i + 1;
}

// W[512][512] fp32 -> Whi/Wlo packed: page = (k>>3) (= 4*kt+g), then
// [c(512)][j(8)], k = 32*kt + 8*g + j. Offset = (k>>3)*4096 + c*8 + (k&7).
__global__ void k_wsplit(const float* __restrict__ W, unsigned short* __restrict__ Whi,
                         unsigned short* __restrict__ Wlo) {
  int t = blockIdx.x * 256 + threadIdx.x;
  if (t >= 512 * 512) return;
  int k = t >> 9, c = t & 511;
  float w = W[t];
  unsigned short hi = f2bf(w);
  unsigned short lo = f2bf(w - bf2f(hi));
  int o = (k >> 3) * 4096 + c * 8 + (k & 7);
  Whi[o] = hi;
  Wlo[o] = lo;
}

// ---------------------------------------------------------------------------
// Fused kernel: block = 256 threads (4 waves), 64 edges, all 512 cols.
// ---------------------------------------------------------------------------
#define KSTEPS 32  // 2 passes x 16 k-chunks of 32

__launch_bounds__(256, 1)
__global__ void k_fused(const float* __restrict__ z, const int* __restrict__ midx,
                        const int* __restrict__ beg, const int* __restrict__ end_,
                        const unsigned short* __restrict__ Whi,
                        const unsigned short* __restrict__ Wlo,
                        const float* __restrict__ bias, const float* __restrict__ gamma,
                        const float* __restrict__ beta, float* __restrict__ out, int E) {
  __shared__ short lA[64 * 512];        // 64 KB: 64 rows x 512 bf16, 16B-chunk XOR-swizzle
  __shared__ short lB[2][16384];        // 2x32 KB: B fragment pages (dbuf)
  __shared__ float lRed[64 * 4];
  __shared__ float lMu[64], lRs[64];

  const int t = threadIdx.x;
  const int w = t >> 6, l = t & 63;
  const int g = l >> 4, l15 = l & 15;
  const int cw = w * 128;
  const int e0 = blockIdx.x * 64;

  // ---- P1: gather + segment mean -> bf16 -> LDS A-tile ----
  // wave w owns rows [16w,16w+16); lane l owns elements [8l,8l+8) of each row.
  for (int i = 0; i < 16; ++i) {
    const int row = w * 16 + i;
    const int e = e0 + row;
    f32x4 a0 = {0.f, 0.f, 0.f, 0.f}, a1 = {0.f, 0.f, 0.f, 0.f};
    if (e < E) {
      const int b = beg[e], en = end_[e];
      int m = b;
      for (; m + 2 <= en; m += 2) {
        const int r0 = midx[m], r1 = midx[m + 1];
        const float* p0 = z + (size_t)r0 * 512 + 8 * l;
        const float* p1 = z + (size_t)r1 * 512 + 8 * l;
        const f32x4 u0 = *(const f32x4*)p0, u1 = *(const f32x4*)(p0 + 4);
        const f32x4 v0 = *(const f32x4*)p1, v1 = *(const f32x4*)(p1 + 4);
        a0 += u0; a1 += u1; a0 += v0; a1 += v1;
      }
      if (m < en) {
        const int r0 = midx[m];
        const float* p0 = z + (size_t)r0 * 512 + 8 * l;
        a0 += *(const f32x4*)p0;
        a1 += *(const f32x4*)(p0 + 4);
      }
      const int cnt = en - b;
      const float den = 1.f / (float)(cnt > 0 ? cnt : 1);
      a0 *= den; a1 *= den;
    }
    ushort8 hv;
#pragma unroll
    for (int j = 0; j < 4; ++j) {
      hv[j] = f2bf(a0[j]);
      hv[4 + j] = f2bf(a1[j]);
    }
    // logical chunk l of row -> swizzled slot (l ^ (row&7)); all 64 slots distinct
    *(ushort8*)&lA[row * 512 + ((l ^ (row & 7)) * 8)] = hv;
  }

  // ---- P2: 2-pass MFMA GEMM, B staged global->LDS double-buffered ----
  f32x4 acc[4][8];
#pragma unroll
  for (int mf = 0; mf < 4; ++mf)
#pragma unroll
    for (int nf = 0; nf < 8; ++nf) acc[mf][nf] = (f32x4){0.f, 0.f, 0.f, 0.f};

  auto stage = [&](int s) {
    const int p = s >> 4, kt = s & 15, buf = s & 1;
    const unsigned short* gb = ((p == 1) ? Wlo : Whi) + (size_t)kt * 16384;
#pragma unroll
    for (int i = 0; i < 8; ++i)
      gld_lds16(gb + (size_t)(i * 256 + t) * 8, &lB[buf][(i * 256 + w * 64) * 8]);
  };

  stage(0);
  for (int s = 0; s < KSTEPS; ++s) {
    __syncthreads();                     // P1 writes + stage(s) landed
    if (s + 1 < KSTEPS) stage(s + 1);
    const int buf = s & 1, kt = s & 15;
    short8 af[4];
#pragma unroll
    for (int mf = 0; mf < 4; ++mf) {
      const int R = 16 * mf + l15;
      af[mf] = *(const short8*)&lA[R * 512 + (((kt * 4 + g) ^ (R & 7)) * 8)];
    }
#pragma unroll
    for (int nf = 0; nf < 8; ++nf) {
      const short8 bf = *(const short8*)&lB[buf][(g * 512 + cw + 16 * nf + l15) * 8];
#pragma unroll
      for (int mf = 0; mf < 4; ++mf)
        acc[mf][nf] = __builtin_amdgcn_mfma_f32_16x16x32_bf16(af[mf], bf, acc[mf][nf], 0, 0, 0);
    }
  }
  __syncthreads();

  // ---- P3: bias + LayerNorm + GELU (exact erf) ----
  float bia[8], gam[8], bet[8];
#pragma unroll
  for (int nf = 0; nf < 8; ++nf) {
    const int col = cw + 16 * nf + l15;
    bia[nf] = bias[col]; gam[nf] = gamma[col]; bet[nf] = beta[col];
  }
#pragma unroll
  for (int mf = 0; mf < 4; ++mf)
#pragma unroll
    for (int nf = 0; nf < 8; ++nf)
#pragma unroll
      for (int r = 0; r < 4; ++r) acc[mf][nf][r] += bia[nf];

  // mean: in-lane sum over 8 cols, 16-lane shfl reduce, cross-wave via LDS
  float s_[4][4];
#pragma unroll
  for (int mf = 0; mf < 4; ++mf)
#pragma unroll
    for (int r = 0; r < 4; ++r) {
      float v = 0.f;
#pragma unroll
      for (int nf = 0; nf < 8; ++nf) v += acc[mf][nf][r];
      v += __shfl_xor(v, 1); v += __shfl_xor(v, 2);
      v += __shfl_xor(v, 4); v += __shfl_xor(v, 8);
      s_[mf][r] = v;
    }
  if (l15 == 0) {
#pragma unroll
    for (int mf = 0; mf < 4; ++mf)
#pragma unroll
      for (int r = 0; r < 4; ++r) lRed[(16 * mf + 4 * g + r) * 4 + w] = s_[mf][r];
  }
  __syncthreads();
  if (t < 64) lMu[t] = (lRed[t * 4] + lRed[t * 4 + 1] + lRed[t * 4 + 2] + lRed[t * 4 + 3]) * (1.f / 512.f);
  __syncthreads();

  float mu_[4][4];
#pragma unroll
  for (int mf = 0; mf < 4; ++mf)
#pragma unroll
    for (int r = 0; r < 4; ++r) mu_[mf][r] = lMu[16 * mf + 4 * g + r];
#pragma unroll
  for (int mf = 0; mf < 4; ++mf)
#pragma unroll
    for (int r = 0; r < 4; ++r) {
      float v = 0.f;
#pragma unroll
      for (int nf = 0; nf < 8; ++nf) {
        const float d = acc[mf][nf][r] - mu_[mf][r];
        v += d * d;
      }
      v += __shfl_xor(v, 1); v += __shfl_xor(v, 2);
      v += __shfl_xor(v, 4); v += __shfl_xor(v, 8);
      s_[mf][r] = v;
    }
  if (l15 == 0) {
#pragma unroll
    for (int mf = 0; mf < 4; ++mf)
#pragma unroll
      for (int r = 0; r < 4; ++r) lRed[(16 * mf + 4 * g + r) * 4 + w] = s_[mf][r];
  }
  __syncthreads();
  if (t < 64) {
    const float sse = lRed[t * 4] + lRed[t * 4 + 1] + lRed[t * 4 + 2] + lRed[t * 4 + 3];
    lRs[t] = rsqrtf(sse * (1.f / 512.f) + 1e-5f);
  }
  __syncthreads();

#pragma unroll
  for (int mf = 0; mf < 4; ++mf)
#pragma unroll
    for (int r = 0; r < 4; ++r) {
      const int row = 16 * mf + 4 * g + r;
      const int er = e0 + row;
      if (er >= E) continue;
      const float mu = lMu[row], rs = lRs[row];
#pragma unroll
      for (int nf = 0; nf < 8; ++nf) {
        const int col = cw + 16 * nf + l15;
        const float x = (acc[mf][nf][r] - mu) * rs * gam[nf] + bet[nf];
        const float y = 0.5f * x * (1.f + erff(x * 0.70710678118654752f));
        out[(size_t)er * 512 + col] = y;
      }
    }
}

// ---------------------------------------------------------------------------
extern "C" void kernel_launch(void* const* d_in, const int* in_sizes, int n_in,
                              void* d_out, int out_size, void* d_ws, size_t ws_size,
                              hipStream_t stream) {
  const float* z = (const float*)d_in[0];
  const float* W = (const float*)d_in[1];
  const float* bias = (const float*)d_in[2];
  const float* gamma = (const float*)d_in[3];
  const float* beta = (const float*)d_in[4];
  const int* midx = (const int*)d_in[5];
  const int* seg = (const int*)d_in[6];
  const int M = in_sizes[5];
  const int E = out_size / 512;

  char* ws = (char*)d_ws;
  size_t off = 0;
  auto alloc = [&](size_t bytes) {
    void* p = ws + off;
    off = (off + bytes + 255) & ~(size_t)255;
    return p;
  };
  int* beg = (int*)alloc((size_t)E * 4);
  int* end_ = (int*)alloc((size_t)E * 4);
  unsigned short* Whi = (unsigned short*)alloc((size_t)512 * 512 * 2);
  unsigned short* Wlo = (unsigned short*)alloc((size_t)512 * 512 * 2);
  (void)ws_size; (void)n_in;

  k_zero<<<(E + 255) / 256, 256, 0, stream>>>(beg, end_, E);
  k_bounds<<<(M + 255) / 256, 256, 0, stream>>>(seg, beg, end_, M);
  k_wsplit<<<(512 * 512 + 255) / 256, 256, 0, stream>>>(W, Whi, Wlo);
  k_fused<<<(E + 63) / 64, 256, 0, stream>>>(z, midx, beg, end_, Whi, Wlo, bias,
                                             gamma, beta, (float*)d_out, E);
}